// Round 6
// baseline (420.386 us; speedup 1.0000x reference)
//
#include <hip/hip_runtime.h>

typedef _Float16 f16;
typedef _Float16 f16x2 __attribute__((ext_vector_type(2)));
typedef _Float16 f16x4v __attribute__((ext_vector_type(4)));
typedef _Float16 f16x8 __attribute__((ext_vector_type(8)));
typedef float f32x4 __attribute__((ext_vector_type(4)));
typedef float f32x16 __attribute__((ext_vector_type(16)));
typedef unsigned int u32x4 __attribute__((ext_vector_type(4)));

#define LOG2E 1.44269504088896f
#define MFMA32(a, b, c) __builtin_amdgcn_mfma_f32_32x32x16_f16(a, b, c, 0, 0, 0)

typedef __attribute__((address_space(1))) const unsigned int* gas_t;
typedef __attribute__((address_space(3))) unsigned int* las_t;

// async global->LDS, 16B per lane: LDS dest = base + lane*16 (wave-uniform base)
static __device__ inline void gload16(const void* g, void* l) {
    __builtin_amdgcn_global_load_lds((gas_t)g, (las_t)l, 16, 0, 0);
}

static __device__ inline f16x8 f16x8_zero() {
    f16x8 v;
#pragma unroll
    for (int i = 0; i < 8; ++i) v[i] = (f16)0.f;
    return v;
}

// v_permlane32_swap_b32: a' = [a.row0 | b.row0], b' = [a.row1 | b.row1]
static __device__ inline void perm32swap(unsigned int& a, unsigned int& b) {
    asm("v_permlane32_swap_b32 %0, %1" : "+v"(a), "+v"(b));
}

// ---------------- Kernel 1: projections ----------------
// Outputs: fO/gO [B*4096][8] f16 (g pre-scaled by log2e), and h in 32x32x16
// FRAGMENT-MAJOR layout: per 16-key group (1024 f16): [cb][nhalf][c&31][n&7];
// a PV A-fragment (16 keys, 32 ch) is one lane-contiguous 1KB block.
__global__ __launch_bounds__(256) void proj_kernel(
    const float* __restrict__ x, const float* __restrict__ Kf,
    const float* __restrict__ Kg, const float* __restrict__ Kh,
    const float* __restrict__ bf, const float* __restrict__ bg,
    const float* __restrict__ bh,
    f16* __restrict__ fO, f16* __restrict__ gO, f16* __restrict__ hF)
{
    __shared__ float KT[80 * 64];   // KT[c][d]: c<8 -> f, 8..15 -> g (scaled), 16..79 -> h
    __shared__ float bias[80];
    const int tid = threadIdx.x;

    for (int i = tid; i < 512; i += 256) {          // Kf/Kg are [64][8]
        int d = i >> 3, j = i & 7;
        KT[j * 64 + d] = Kf[i];
        KT[(8 + j) * 64 + d] = Kg[i] * LOG2E;
    }
    for (int i = tid; i < 4096; i += 256) {         // Kh is [64][64]
        int d = i >> 6, c = i & 63;
        KT[(16 + c) * 64 + d] = Kh[i];
    }
    if (tid < 8) { bias[tid] = bf[tid]; bias[8 + tid] = bg[tid] * LOG2E; }
    if (tid >= 16 && tid < 80) bias[tid] = bh[tid - 16];
    __syncthreads();

    const int quarter = tid >> 6;                   // wave id: which 20 output channels
    const int px = blockIdx.x * 64 + (tid & 63);    // pixel (b*4096 + n)
    const float4* xp = (const float4*)(x + (size_t)px * 64);
    float4 xr[16];
#pragma unroll
    for (int i = 0; i < 16; ++i) xr[i] = xp[i];

    float res[20];
    const int c0 = quarter * 20;
#pragma unroll
    for (int cc = 0; cc < 20; ++cc) {
        const int c = c0 + cc;
        float acc = bias[c];
        const float4* wv = (const float4*)(KT + c * 64);
#pragma unroll
        for (int i = 0; i < 16; ++i) {
            float4 w = wv[i];
            acc = fmaf(xr[i].x, w.x, acc);
            acc = fmaf(xr[i].y, w.y, acc);
            acc = fmaf(xr[i].z, w.z, acc);
            acc = fmaf(xr[i].w, w.w, acc);
        }
        res[cc] = acc;
    }

    const int b = px >> 12, n = px & 4095;
    const size_t hbase = (size_t)b * 262144 + (size_t)(n >> 4) * 1024
                       + (size_t)((n >> 3) & 1) * 256 + (n & 7);
    if (quarter == 0) {
        f16x8 fv, gv;
#pragma unroll
        for (int j = 0; j < 8; ++j) { fv[j] = (f16)res[j]; gv[j] = (f16)res[8 + j]; }
        *(f16x8*)(fO + (size_t)px * 8) = fv;
        *(f16x8*)(gO + (size_t)px * 8) = gv;
#pragma unroll
        for (int cc = 16; cc < 20; ++cc) {
            const int hc = c0 + cc - 16;
            hF[hbase + (hc >> 5) * 512 + (hc & 31) * 8] = (f16)res[cc];
        }
    } else {
#pragma unroll
        for (int cc = 0; cc < 20; ++cc) {
            const int hc = c0 + cc - 16;
            hF[hbase + (hc >> 5) * 512 + (hc & 31) * 8] = (f16)res[cc];
        }
    }
}

// ---------------- Kernel 2: flash attention (32x32 MFMA, split-K, LDS-staged) --
// Block = 4 waves x 32 q-rows = 128 q. Per 64-key tile: h (8KB) + f (1KB) staged
// into LDS via global_load_lds (zero VGPR cost), double-buffered, one
// __syncthreads per iter. Split-K x8 -> 2048 blocks = 8 blocks/CU = 32 waves/CU
// (full occupancy; the per-iter serial chain is hidden by 8 waves/SIMD).
// Swapped QK^T via mfma_32x32x16_f16; P assembled in-register via
// cvt_pkrtz + permlane32_swap; PV O^T = H^T P^T from LDS fragments. Defer-max.
template<int NSPLIT>
__global__ __launch_bounds__(256, 8) void attn6_kernel(
    const f16* __restrict__ fO, const f16* __restrict__ gO,
    const f16* __restrict__ hF, const float* __restrict__ x,
    const float* __restrict__ gamma, float* __restrict__ out,
    f16* __restrict__ po, float* __restrict__ pml)
{
    __shared__ __align__(16) char lds[2][9216];   // [buf][ h:8192 | f:1024 ]

    const int tid  = threadIdx.x;
    const int w    = tid >> 6;
    const int lane = tid & 63;
    const int q5   = lane & 31;
    const int hi   = lane >> 5;

    const int b = blockIdx.x & 7;
    int kc, qt;
    if (NSPLIT == 8)      { kc = (blockIdx.x >> 3) & 7; qt = blockIdx.x >> 6; }
    else if (NSPLIT == 4) { kc = (blockIdx.x >> 3) & 3; qt = blockIdx.x >> 5; }
    else if (NSPLIT == 2) { kc = (blockIdx.x >> 3) & 1; qt = blockIdx.x >> 4; }
    else                  { kc = 0;                     qt = blockIdx.x >> 3; }

    const int KEYS = 4096 / NSPLIT;
    const int NIT  = KEYS / 64;
    const int k0   = kc * KEYS;
    const int qrow = qt * 128 + w * 32 + q5;

    // global tile bases (bytes)
    const char* hTile = (const char*)hF + ((size_t)b * 262144 + (size_t)k0 * 64) * 2;
    const char* fTile = (const char*)fO + ((size_t)b * 32768 + (size_t)k0 * 8) * 2;

    // QK B operand: lanes<32 hold g[q][0..7] (k rows 0..7); lanes>=32 zero (K pad 8->16).
    f16x8 gfrag = f16x8_zero();
    if (lane < 32) gfrag = *(const f16x8*)(gO + (size_t)b * 32768 + (size_t)qrow * 8);

    f32x16 acc0, acc1;
#pragma unroll
    for (int i = 0; i < 16; ++i) { acc0[i] = 0.f; acc1[i] = 0.f; }
    float mrun = -1e30f, lpart = 0.f;

    // ---- stage tile 0 ----
    {
        const char* hg = hTile + w * 2048 + lane * 16;
        char* hl = &lds[0][0] + w * 2048;
        gload16(hg, hl);
        gload16(hg + 1024, hl + 1024);
        if (w == 3) gload16(fTile + lane * 16, &lds[0][8192]);
    }
    __syncthreads();

    for (int t = 0; t < NIT; ++t) {
        const int cur = t & 1;
        if (t + 1 < NIT) {                          // issue next-tile stage (async)
            const char* hg = hTile + (size_t)(t + 1) * 8192 + w * 2048 + lane * 16;
            char* hl = &lds[cur ^ 1][0] + w * 2048;
            gload16(hg, hl);
            gload16(hg + 1024, hl + 1024);
            if (w == 3) gload16(fTile + (size_t)(t + 1) * 1024 + lane * 16, &lds[cur ^ 1][8192]);
        }

        const f16* hl = (const f16*)&lds[cur][0];
        const f16* fl = (const f16*)&lds[cur][8192];

        // ---- QK^T: S^T[key][q], q = lane&31 ----
        const f16x8 fa0 = *(const f16x8*)(fl + q5 * 8);          // keys 0..31
        const f16x8 fa1 = *(const f16x8*)(fl + 256 + q5 * 8);    // keys 32..63
        f32x16 zc;
#pragma unroll
        for (int i = 0; i < 16; ++i) zc[i] = 0.f;
        f32x16 s0 = MFMA32(fa0, gfrag, zc);
        f32x16 s1 = MFMA32(fa1, gfrag, zc);

        // ---- online softmax (log2 units) ----
        f32x16 mt;
#pragma unroll
        for (int i = 0; i < 16; ++i) mt[i] = fmaxf(s0[i], s1[i]);
#pragma unroll
        for (int st = 8; st >= 1; st >>= 1)
#pragma unroll
            for (int i = 0; i < st; ++i) mt[i] = fmaxf(mt[i], mt[i + st]);
        float m8 = fmaxf(mt[0], __shfl_xor(mt[0], 32));

        if (__any(m8 > mrun + 8.f)) {                    // defer-max (T13)
            const float mnew = fmaxf(mrun, m8);
            const float sc = exp2f(mrun - mnew);
            mrun = mnew;
#pragma unroll
            for (int i = 0; i < 16; ++i) { acc0[i] *= sc; acc1[i] *= sc; }
            lpart *= sc;
        }

#pragma unroll
        for (int i = 0; i < 16; ++i) {                   // exp in place
            s0[i] = exp2f(s0[i] - mrun);
            s1[i] = exp2f(s1[i] - mrun);
        }

        // ---- pack to f16 pairs (consecutive regs = consecutive keys) ----
        unsigned int wr[16];
#pragma unroll
        for (int i = 0; i < 8; ++i) {
            wr[i]     = __builtin_bit_cast(unsigned int, __builtin_amdgcn_cvt_pkrtz(s0[2 * i], s0[2 * i + 1]));
            wr[8 + i] = __builtin_bit_cast(unsigned int, __builtin_amdgcn_cvt_pkrtz(s1[2 * i], s1[2 * i + 1]));
        }

        // ---- l partial via v_pk_add_f16 tree over own 32 keys ----
        {
            f16x2 s8[8];
#pragma unroll
            for (int i = 0; i < 8; ++i)
                s8[i] = __builtin_bit_cast(f16x2, wr[i]) + __builtin_bit_cast(f16x2, wr[8 + i]);
#pragma unroll
            for (int st = 4; st >= 1; st >>= 1)
#pragma unroll
                for (int i = 0; i < st; ++i) s8[i] = s8[i] + s8[i + st];
            lpart += (float)s8[0][0] + (float)s8[0][1];
        }

        // ---- assemble PV B-fragments in-register: 8 permlane32_swap ----
        perm32swap(wr[0], wr[2]);   perm32swap(wr[1], wr[3]);    // keys  0..15
        perm32swap(wr[4], wr[6]);   perm32swap(wr[5], wr[7]);    // keys 16..31
        perm32swap(wr[8], wr[10]);  perm32swap(wr[9], wr[11]);   // keys 32..47
        perm32swap(wr[12], wr[14]); perm32swap(wr[13], wr[15]);  // keys 48..63

        // ---- PV: O^T[c][q] += H^T[c][k] P^T[k][q], fragments from LDS ----
#pragma unroll
        for (int kk = 0; kk < 4; ++kk) {
            u32x4 tv;
            tv[0] = wr[kk * 4 + 0]; tv[1] = wr[kk * 4 + 1];
            tv[2] = wr[kk * 4 + 2]; tv[3] = wr[kk * 4 + 3];
            const f16x8 pf = __builtin_bit_cast(f16x8, tv);
            const f16x8 ha0 = *(const f16x8*)(hl + kk * 1024 + lane * 8);
            const f16x8 ha1 = *(const f16x8*)(hl + kk * 1024 + 512 + lane * 8);
            acc0 = MFMA32(ha0, pf, acc0);
            acc1 = MFMA32(ha1, pf, acc1);
        }

        if (t + 1 < NIT) __syncthreads();   // drains vmcnt(0)+lgkmcnt(0): staged tile ready
    }

    lpart += __shfl_xor(lpart, 32);

    if (NSPLIT == 1) {
        const float rin = 1.f / lpart;
        const float gm = gamma[0];
        const size_t qg = (size_t)b * 4096 + qrow;
#pragma unroll
        for (int cb = 0; cb < 2; ++cb)
#pragma unroll
            for (int r = 0; r < 4; ++r) {
                const size_t o = qg * 64 + cb * 32 + r * 8 + hi * 4;
                f32x4 v;
#pragma unroll
                for (int j = 0; j < 4; ++j) {
                    const float a = (cb == 0) ? acc0[4 * r + j] : acc1[4 * r + j];
                    v[j] = fmaf(gm, a * rin, x[o + j]);
                }
                *(f32x4*)(out + o) = v;
            }
    } else {
        f16* pob = po + (size_t)((kc * 8 + b) * 128 + qt * 4 + w) * 2048;
#pragma unroll
        for (int cb = 0; cb < 2; ++cb)
#pragma unroll
            for (int r = 0; r < 4; ++r) {
                uint2 v;
                const float a0 = (cb == 0) ? acc0[4 * r + 0] : acc1[4 * r + 0];
                const float a1 = (cb == 0) ? acc0[4 * r + 1] : acc1[4 * r + 1];
                const float a2 = (cb == 0) ? acc0[4 * r + 2] : acc1[4 * r + 2];
                const float a3 = (cb == 0) ? acc0[4 * r + 3] : acc1[4 * r + 3];
                v.x = __builtin_bit_cast(unsigned int, __builtin_amdgcn_cvt_pkrtz(a0, a1));
                v.y = __builtin_bit_cast(unsigned int, __builtin_amdgcn_cvt_pkrtz(a2, a3));
                *(uint2*)(pob + (cb * 4 + r) * 256 + lane * 4) = v;
            }
        if (lane < 32) {
            float2 ml; ml.x = mrun; ml.y = lpart;
            *(float2*)(pml + ((size_t)(kc * 8 + b) * 4096 + qrow) * 2) = ml;
        }
    }
}

// ---------------- Kernel 3: split-K combine (po in f16) ----------------
template<int NS>
__global__ __launch_bounds__(256) void combine_kernel(
    const f16* __restrict__ po, const float* __restrict__ pml,
    const float* __restrict__ x, const float* __restrict__ gamma,
    float* __restrict__ out)
{
    const int t    = blockIdx.x * 256 + threadIdx.x;    // 524288 threads
    const int lane = t & 63;
    const int r    = (t >> 6) & 3;
    const int cb   = (t >> 8) & 1;
    const int w    = (t >> 9) & 3;
    const int qt   = (t >> 11) & 31;
    const int b    = (t >> 16) & 7;
    const int q    = qt * 128 + w * 32 + (lane & 31);
    const int c    = cb * 32 + r * 8 + (lane >> 5) * 4;

    float m[NS], l[NS];
    float M = -1e30f;
#pragma unroll
    for (int kc = 0; kc < NS; ++kc) {
        const float2 ml = *(const float2*)(pml + ((size_t)(kc * 8 + b) * 4096 + q) * 2);
        m[kc] = ml.x; l[kc] = ml.y;
        M = fmaxf(M, ml.x);
    }
    float denom = 0.f;
    f32x4 num;
#pragma unroll
    for (int j = 0; j < 4; ++j) num[j] = 0.f;
#pragma unroll
    for (int kc = 0; kc < NS; ++kc) {
        const float e = exp2f(m[kc] - M);
        denom = fmaf(e, l[kc], denom);
        const f16x4v v = *(const f16x4v*)(po + (size_t)((kc * 8 + b) * 128 + qt * 4 + w) * 2048
                                             + (cb * 4 + r) * 256 + lane * 4);
#pragma unroll
        for (int j = 0; j < 4; ++j) num[j] = fmaf(e, (float)v[j], num[j]);
    }
    const float sc = gamma[0] / denom;
    const size_t o = ((size_t)b * 4096 + q) * 64 + c;
    const f32x4 xv = *(const f32x4*)(x + o);
    f32x4 ov;
#pragma unroll
    for (int j = 0; j < 4; ++j) ov[j] = fmaf(sc, num[j], xv[j]);
    *(f32x4*)(out + o) = ov;
}

extern "C" void kernel_launch(void* const* d_in, const int* in_sizes, int n_in,
                              void* d_out, int out_size, void* d_ws, size_t ws_size,
                              hipStream_t stream) {
    const float* x     = (const float*)d_in[0];
    const float* Kf    = (const float*)d_in[1];
    const float* Kg    = (const float*)d_in[2];
    const float* Kh    = (const float*)d_in[3];
    const float* bf    = (const float*)d_in[4];
    const float* bg    = (const float*)d_in[5];
    const float* bh    = (const float*)d_in[6];
    const float* gamma = (const float*)d_in[7];
    float* out = (float*)d_out;

    f16* fO = (f16*)d_ws;                               // 512 KB
    f16* gO = (f16*)((char*)d_ws + (512 << 10));        // 512 KB
    f16* hF = (f16*)((char*)d_ws + (1 << 20));          // 4 MB (fragment-major h)
    f16* po = (f16*)((char*)d_ws + (5 << 20));          // NSPLIT*4 MB partial O (f16)

    const size_t need8 = ((size_t)5 << 20) + ((size_t)32 << 20) + ((size_t)2 << 20);
    const size_t need4 = ((size_t)5 << 20) + ((size_t)16 << 20) + ((size_t)1 << 20);
    const size_t need2 = ((size_t)5 << 20) + ((size_t)8 << 20) + ((size_t)1 << 19);

    hipLaunchKernelGGL(proj_kernel, dim3(512), dim3(256), 0, stream,
                       x, Kf, Kg, Kh, bf, bg, bh, fO, gO, hF);
    if (ws_size >= need8) {
        float* pml = (float*)((char*)d_ws + (37u << 20));
        hipLaunchKernelGGL((attn6_kernel<8>), dim3(2048), dim3(256), 0, stream,
                           fO, gO, hF, x, gamma, out, po, pml);
        hipLaunchKernelGGL((combine_kernel<8>), dim3(2048), dim3(256), 0, stream,
                           po, pml, x, gamma, out);
    } else if (ws_size >= need4) {
        float* pml = (float*)((char*)d_ws + (21u << 20));
        hipLaunchKernelGGL((attn6_kernel<4>), dim3(1024), dim3(256), 0, stream,
                           fO, gO, hF, x, gamma, out, po, pml);
        hipLaunchKernelGGL((combine_kernel<4>), dim3(2048), dim3(256), 0, stream,
                           po, pml, x, gamma, out);
    } else if (ws_size >= need2) {
        float* pml = (float*)((char*)d_ws + (13u << 20));
        hipLaunchKernelGGL((attn6_kernel<2>), dim3(512), dim3(256), 0, stream,
                           fO, gO, hF, x, gamma, out, po, pml);
        hipLaunchKernelGGL((combine_kernel<2>), dim3(2048), dim3(256), 0, stream,
                           po, pml, x, gamma, out);
    } else {
        hipLaunchKernelGGL((attn6_kernel<1>), dim3(256), dim3(256), 0, stream,
                           fO, gO, hF, x, gamma, out, po, (float*)po);
    }
}

// Round 7
// 87.152 us; speedup vs baseline: 4.8236x; 4.8236x over previous
//
#include <hip/hip_runtime.h>

typedef _Float16 f16;
typedef _Float16 f16x2 __attribute__((ext_vector_type(2)));
typedef _Float16 f16x4v __attribute__((ext_vector_type(4)));
typedef _Float16 f16x8 __attribute__((ext_vector_type(8)));
typedef float f32x4 __attribute__((ext_vector_type(4)));
typedef float f32x16 __attribute__((ext_vector_type(16)));
typedef unsigned int u32x4 __attribute__((ext_vector_type(4)));

#define LOG2E 1.44269504088896f
#define MFMA32(a, b, c) __builtin_amdgcn_mfma_f32_32x32x16_f16(a, b, c, 0, 0, 0)

typedef __attribute__((address_space(1))) const unsigned int* gas_t;
typedef __attribute__((address_space(3))) unsigned int* las_t;

// async global->LDS, 16B per lane: LDS dest = wave-uniform base + lane*16
static __device__ inline void gload16(const void* g, void* l) {
    __builtin_amdgcn_global_load_lds((gas_t)g, (las_t)l, 16, 0, 0);
}

static __device__ inline f16x8 f16x8_zero() {
    f16x8 v;
#pragma unroll
    for (int i = 0; i < 8; ++i) v[i] = (f16)0.f;
    return v;
}

// v_permlane32_swap_b32: a' = [a.row0 | b.row0], b' = [a.row1 | b.row1]
static __device__ inline void perm32swap(unsigned int& a, unsigned int& b) {
    asm("v_permlane32_swap_b32 %0, %1" : "+v"(a), "+v"(b));
}

// ---------------- Kernel 1: projections (unchanged from r5) ----------------
__global__ __launch_bounds__(256) void proj_kernel(
    const float* __restrict__ x, const float* __restrict__ Kf,
    const float* __restrict__ Kg, const float* __restrict__ Kh,
    const float* __restrict__ bf, const float* __restrict__ bg,
    const float* __restrict__ bh,
    f16* __restrict__ fO, f16* __restrict__ gO, f16* __restrict__ hF)
{
    __shared__ float KT[80 * 64];   // KT[c][d]: c<8 -> f, 8..15 -> g (scaled), 16..79 -> h
    __shared__ float bias[80];
    const int tid = threadIdx.x;

    for (int i = tid; i < 512; i += 256) {          // Kf/Kg are [64][8]
        int d = i >> 3, j = i & 7;
        KT[j * 64 + d] = Kf[i];
        KT[(8 + j) * 64 + d] = Kg[i] * LOG2E;
    }
    for (int i = tid; i < 4096; i += 256) {         // Kh is [64][64]
        int d = i >> 6, c = i & 63;
        KT[(16 + c) * 64 + d] = Kh[i];
    }
    if (tid < 8) { bias[tid] = bf[tid]; bias[8 + tid] = bg[tid] * LOG2E; }
    if (tid >= 16 && tid < 80) bias[tid] = bh[tid - 16];
    __syncthreads();

    const int quarter = tid >> 6;
    const int px = blockIdx.x * 64 + (tid & 63);    // pixel (b*4096 + n)
    const float4* xp = (const float4*)(x + (size_t)px * 64);
    float4 xr[16];
#pragma unroll
    for (int i = 0; i < 16; ++i) xr[i] = xp[i];

    float res[20];
    const int c0 = quarter * 20;
#pragma unroll
    for (int cc = 0; cc < 20; ++cc) {
        const int c = c0 + cc;
        float acc = bias[c];
        const float4* wv = (const float4*)(KT + c * 64);
#pragma unroll
        for (int i = 0; i < 16; ++i) {
            float4 w = wv[i];
            acc = fmaf(xr[i].x, w.x, acc);
            acc = fmaf(xr[i].y, w.y, acc);
            acc = fmaf(xr[i].z, w.z, acc);
            acc = fmaf(xr[i].w, w.w, acc);
        }
        res[cc] = acc;
    }

    const int b = px >> 12, n = px & 4095;
    const size_t hbase = (size_t)b * 262144 + (size_t)(n >> 4) * 1024
                       + (size_t)((n >> 3) & 1) * 256 + (n & 7);
    if (quarter == 0) {
        f16x8 fv, gv;
#pragma unroll
        for (int j = 0; j < 8; ++j) { fv[j] = (f16)res[j]; gv[j] = (f16)res[8 + j]; }
        *(f16x8*)(fO + (size_t)px * 8) = fv;
        *(f16x8*)(gO + (size_t)px * 8) = gv;
#pragma unroll
        for (int cc = 16; cc < 20; ++cc) {
            const int hc = c0 + cc - 16;
            hF[hbase + (hc >> 5) * 512 + (hc & 31) * 8] = (f16)res[cc];
        }
    } else {
#pragma unroll
        for (int cc = 0; cc < 20; ++cc) {
            const int hc = c0 + cc - 16;
            hF[hbase + (hc >> 5) * 512 + (hc & 31) * 8] = (f16)res[cc];
        }
    }
}

// ---------------- Kernel 2: flash attention (pipelined, counted-vmcnt) ------
// 4-deep LDS ring of 64-key tiles. Iteration t: stage(t+3) async; softmax+PV on
// s(t) (computed LAST iter); QK produces s(t+1) (consumed NEXT iter). Barrier =
// raw s_barrier + counted vmcnt (2 tiles stay in flight, never drained to 0).
// Per-wave loads/tile uniform: waves 0-2: 2, wave 3: 3 -> literal vmcnt(2|3).
template<int NSPLIT>
__global__ __launch_bounds__(256, 4) void attn7_kernel(
    const f16* __restrict__ fO, const f16* __restrict__ gO,
    const f16* __restrict__ hF, const float* __restrict__ x,
    const float* __restrict__ gamma, float* __restrict__ out,
    f16* __restrict__ po, float* __restrict__ pml)
{
    __shared__ __align__(16) char lds[4][9216];   // ring: [buf][ h:8192 | f:1024 ]

    const int tid  = threadIdx.x;
    const int w    = tid >> 6;
    const int lane = tid & 63;
    const int q5   = lane & 31;
    const int hi   = lane >> 5;

    const int b = blockIdx.x & 7;
    int kc, qt;
    if (NSPLIT == 4)      { kc = (blockIdx.x >> 3) & 3; qt = blockIdx.x >> 5; }
    else if (NSPLIT == 2) { kc = (blockIdx.x >> 3) & 1; qt = blockIdx.x >> 4; }
    else                  { kc = 0;                     qt = blockIdx.x >> 3; }

    const int KEYS = 4096 / NSPLIT;
    const int NIT  = KEYS / 64;                   // 16 / 32 / 64 (even, >=4)
    const int k0   = kc * KEYS;
    const int qrow = qt * 128 + w * 32 + q5;

    const char* hTile = (const char*)hF + ((size_t)b * 262144 + (size_t)k0 * 64) * 2;
    const char* fTile = (const char*)fO + ((size_t)b * 32768 + (size_t)k0 * 8) * 2;

    // QK B operand: lanes<32 hold g[q][0..7]; lanes>=32 zero (K pad 8->16).
    f16x8 gfrag = f16x8_zero();
    if (lane < 32) gfrag = *(const f16x8*)(gO + (size_t)b * 32768 + (size_t)qrow * 8);
    asm volatile("s_waitcnt vmcnt(0)" ::: "memory");   // clean vmcnt bookkeeping

    f32x16 acc0, acc1;
#pragma unroll
    for (int i = 0; i < 16; ++i) { acc0[i] = 0.f; acc1[i] = 0.f; }
    float mrun = -1e30f, lpart = 0.f;

#define STAGE(KT_, BI_) do {                                                    \
        const char* hg_ = hTile + (size_t)(KT_) * 8192 + w * 2048 + (size_t)lane * 16; \
        char* hl_ = &lds[BI_][0] + w * 2048;                                    \
        gload16(hg_, hl_);                                                      \
        gload16(hg_ + 1024, hl_ + 1024);                                        \
        if (w == 3) gload16(fTile + (size_t)(KT_) * 1024 + lane * 16, &lds[BI_][8192]); \
    } while (0)

#define TILE_BARRIER() do {                                                     \
        if (w == 3) asm volatile("s_waitcnt vmcnt(3)" ::: "memory");            \
        else        asm volatile("s_waitcnt vmcnt(2)" ::: "memory");            \
        __builtin_amdgcn_s_barrier();                                           \
        __builtin_amdgcn_sched_barrier(0);                                      \
    } while (0)

    // QK from LDS buffer BI -> scores (so0: keys 0..31, so1: keys 32..63)
#define QK_STEP(BI_, SO0_, SO1_) do {                                           \
        const f16* fl_ = (const f16*)&lds[BI_][8192];                           \
        const f16x8 fa0_ = *(const f16x8*)(fl_ + q5 * 8);                       \
        const f16x8 fa1_ = *(const f16x8*)(fl_ + 256 + q5 * 8);                 \
        f32x16 zc_;                                                             \
        _Pragma("unroll") for (int i_ = 0; i_ < 16; ++i_) zc_[i_] = 0.f;        \
        SO0_ = MFMA32(fa0_, gfrag, zc_);                                        \
        SO1_ = MFMA32(fa1_, gfrag, zc_);                                        \
    } while (0)

    // softmax(SI) -> wr[16] packed f16 + lpart; then permlane + PV from buf BI
#define SM_PV(SI0_, SI1_, BI_) do {                                             \
        f32x16 mt_;                                                             \
        _Pragma("unroll") for (int i_ = 0; i_ < 16; ++i_)                       \
            mt_[i_] = fmaxf(SI0_[i_], SI1_[i_]);                                \
        _Pragma("unroll") for (int st_ = 8; st_ >= 1; st_ >>= 1)                \
            _Pragma("unroll") for (int i_ = 0; i_ < st_; ++i_)                  \
                mt_[i_] = fmaxf(mt_[i_], mt_[i_ + st_]);                        \
        float m8_ = fmaxf(mt_[0], __shfl_xor(mt_[0], 32));                      \
        if (__any(m8_ > mrun + 8.f)) {                                          \
            const float mnew_ = fmaxf(mrun, m8_);                               \
            const float sc_ = exp2f(mrun - mnew_);                              \
            mrun = mnew_;                                                       \
            _Pragma("unroll") for (int i_ = 0; i_ < 16; ++i_)                   \
                { acc0[i_] *= sc_; acc1[i_] *= sc_; }                           \
            lpart *= sc_;                                                       \
        }                                                                       \
        _Pragma("unroll") for (int i_ = 0; i_ < 16; ++i_) {                     \
            SI0_[i_] = exp2f(SI0_[i_] - mrun);                                  \
            SI1_[i_] = exp2f(SI1_[i_] - mrun);                                  \
        }                                                                       \
        unsigned int wr_[16];                                                   \
        _Pragma("unroll") for (int i_ = 0; i_ < 8; ++i_) {                      \
            wr_[i_]     = __builtin_bit_cast(unsigned int,                      \
                __builtin_amdgcn_cvt_pkrtz(SI0_[2 * i_], SI0_[2 * i_ + 1]));    \
            wr_[8 + i_] = __builtin_bit_cast(unsigned int,                      \
                __builtin_amdgcn_cvt_pkrtz(SI1_[2 * i_], SI1_[2 * i_ + 1]));    \
        }                                                                       \
        {                                                                       \
            f16x2 s8_[8];                                                       \
            _Pragma("unroll") for (int i_ = 0; i_ < 8; ++i_)                    \
                s8_[i_] = __builtin_bit_cast(f16x2, wr_[i_])                    \
                        + __builtin_bit_cast(f16x2, wr_[8 + i_]);               \
            _Pragma("unroll") for (int st_ = 4; st_ >= 1; st_ >>= 1)            \
                _Pragma("unroll") for (int i_ = 0; i_ < st_; ++i_)              \
                    s8_[i_] = s8_[i_] + s8_[i_ + st_];                          \
            lpart += (float)s8_[0][0] + (float)s8_[0][1];                       \
        }                                                                       \
        perm32swap(wr_[0], wr_[2]);   perm32swap(wr_[1], wr_[3]);               \
        perm32swap(wr_[4], wr_[6]);   perm32swap(wr_[5], wr_[7]);               \
        perm32swap(wr_[8], wr_[10]);  perm32swap(wr_[9], wr_[11]);              \
        perm32swap(wr_[12], wr_[14]); perm32swap(wr_[13], wr_[15]);             \
        const f16* hl_ = (const f16*)&lds[BI_][0];                              \
        _Pragma("unroll") for (int kk_ = 0; kk_ < 4; ++kk_) {                   \
            u32x4 tv_;                                                          \
            tv_[0] = wr_[kk_ * 4 + 0]; tv_[1] = wr_[kk_ * 4 + 1];               \
            tv_[2] = wr_[kk_ * 4 + 2]; tv_[3] = wr_[kk_ * 4 + 3];               \
            const f16x8 pf_ = __builtin_bit_cast(f16x8, tv_);                   \
            const f16x8 ha0_ = *(const f16x8*)(hl_ + kk_ * 1024 + lane * 8);    \
            const f16x8 ha1_ = *(const f16x8*)(hl_ + kk_ * 1024 + 512 + lane * 8); \
            acc0 = MFMA32(ha0_, pf_, acc0);                                     \
            acc1 = MFMA32(ha1_, pf_, acc1);                                     \
        }                                                                       \
    } while (0)

    // ---- prologue: stage tiles 0,1,2; ensure 0,1 ready; compute s(0) ----
    STAGE(0, 0);
    STAGE(1, 1);
    STAGE(2, 2);
    TILE_BARRIER();            // waits own tiles 0,1 done (2|3 remain for tile 2)

    f32x16 sA0, sA1, sB0, sB1;
    QK_STEP(0, sA0, sA1);      // s(0)

    // ---- main loop, unrolled x2 (ping-pong sA/sB, no vector copies) ----
    for (int t = 0; t < NIT; t += 2) {
        // half-iter t: softmax+PV on sA = s(t); QK -> sB = s(t+1)
        {
            const int kt = (t + 3 < NIT) ? t + 3 : NIT - 1;
            STAGE(kt, (t + 3) & 3);
            SM_PV(sA0, sA1, t & 3);
            QK_STEP((t + 1) & 3, sB0, sB1);
            TILE_BARRIER();                      // ensures tile t+2 ready
        }
        // half-iter t+1: softmax+PV on sB = s(t+1); QK -> sA = s(t+2)
        {
            const int kt = (t + 4 < NIT) ? t + 4 : NIT - 1;
            STAGE(kt, (t + 4) & 3);
            SM_PV(sB0, sB1, (t + 1) & 3);
            QK_STEP((t + 2) & 3, sA0, sA1);      // garbage on final pair; never used
            TILE_BARRIER();                      // ensures tile t+3 ready
        }
    }
#undef STAGE
#undef TILE_BARRIER
#undef QK_STEP
#undef SM_PV

    lpart += __shfl_xor(lpart, 32);

    if (NSPLIT == 1) {
        const float rin = 1.f / lpart;
        const float gm = gamma[0];
        const size_t qg = (size_t)b * 4096 + qrow;
#pragma unroll
        for (int cb = 0; cb < 2; ++cb)
#pragma unroll
            for (int r = 0; r < 4; ++r) {
                const size_t o = qg * 64 + cb * 32 + r * 8 + hi * 4;
                f32x4 v;
#pragma unroll
                for (int j = 0; j < 4; ++j) {
                    const float a = (cb == 0) ? acc0[4 * r + j] : acc1[4 * r + j];
                    v[j] = fmaf(gm, a * rin, x[o + j]);
                }
                *(f32x4*)(out + o) = v;
            }
    } else {
        f16* pob = po + (size_t)((kc * 8 + b) * 128 + qt * 4 + w) * 2048;
#pragma unroll
        for (int cb = 0; cb < 2; ++cb)
#pragma unroll
            for (int r = 0; r < 4; ++r) {
                uint2 v;
                const float a0 = (cb == 0) ? acc0[4 * r + 0] : acc1[4 * r + 0];
                const float a1 = (cb == 0) ? acc0[4 * r + 1] : acc1[4 * r + 1];
                const float a2 = (cb == 0) ? acc0[4 * r + 2] : acc1[4 * r + 2];
                const float a3 = (cb == 0) ? acc0[4 * r + 3] : acc1[4 * r + 3];
                v.x = __builtin_bit_cast(unsigned int, __builtin_amdgcn_cvt_pkrtz(a0, a1));
                v.y = __builtin_bit_cast(unsigned int, __builtin_amdgcn_cvt_pkrtz(a2, a3));
                *(uint2*)(pob + (cb * 4 + r) * 256 + lane * 4) = v;
            }
        if (lane < 32) {
            float2 ml; ml.x = mrun; ml.y = lpart;
            *(float2*)(pml + ((size_t)(kc * 8 + b) * 4096 + qrow) * 2) = ml;
        }
    }
}

// ---------------- Kernel 3: split-K combine (po in f16) ----------------
template<int NS>
__global__ __launch_bounds__(256) void combine_kernel(
    const f16* __restrict__ po, const float* __restrict__ pml,
    const float* __restrict__ x, const float* __restrict__ gamma,
    float* __restrict__ out)
{
    const int t    = blockIdx.x * 256 + threadIdx.x;    // 524288 threads
    const int lane = t & 63;
    const int r    = (t >> 6) & 3;
    const int cb   = (t >> 8) & 1;
    const int w    = (t >> 9) & 3;
    const int qt   = (t >> 11) & 31;
    const int b    = (t >> 16) & 7;
    const int q    = qt * 128 + w * 32 + (lane & 31);
    const int c    = cb * 32 + r * 8 + (lane >> 5) * 4;

    float m[NS], l[NS];
    float M = -1e30f;
#pragma unroll
    for (int kc = 0; kc < NS; ++kc) {
        const float2 ml = *(const float2*)(pml + ((size_t)(kc * 8 + b) * 4096 + q) * 2);
        m[kc] = ml.x; l[kc] = ml.y;
        M = fmaxf(M, ml.x);
    }
    float denom = 0.f;
    f32x4 num;
#pragma unroll
    for (int j = 0; j < 4; ++j) num[j] = 0.f;
#pragma unroll
    for (int kc = 0; kc < NS; ++kc) {
        const float e = exp2f(m[kc] - M);
        denom = fmaf(e, l[kc], denom);
        const f16x4v v = *(const f16x4v*)(po + (size_t)((kc * 8 + b) * 128 + qt * 4 + w) * 2048
                                             + (cb * 4 + r) * 256 + lane * 4);
#pragma unroll
        for (int j = 0; j < 4; ++j) num[j] = fmaf(e, (float)v[j], num[j]);
    }
    const float sc = gamma[0] / denom;
    const size_t o = ((size_t)b * 4096 + q) * 64 + c;
    const f32x4 xv = *(const f32x4*)(x + o);
    f32x4 ov;
#pragma unroll
    for (int j = 0; j < 4; ++j) ov[j] = fmaf(sc, num[j], xv[j]);
    *(f32x4*)(out + o) = ov;
}

extern "C" void kernel_launch(void* const* d_in, const int* in_sizes, int n_in,
                              void* d_out, int out_size, void* d_ws, size_t ws_size,
                              hipStream_t stream) {
    const float* x     = (const float*)d_in[0];
    const float* Kf    = (const float*)d_in[1];
    const float* Kg    = (const float*)d_in[2];
    const float* Kh    = (const float*)d_in[3];
    const float* bf    = (const float*)d_in[4];
    const float* bg    = (const float*)d_in[5];
    const float* bh    = (const float*)d_in[6];
    const float* gamma = (const float*)d_in[7];
    float* out = (float*)d_out;

    f16* fO = (f16*)d_ws;                               // 512 KB
    f16* gO = (f16*)((char*)d_ws + (512 << 10));        // 512 KB
    f16* hF = (f16*)((char*)d_ws + (1 << 20));          // 4 MB (fragment-major h)
    f16* po = (f16*)((char*)d_ws + (5 << 20));          // NSPLIT*4 MB partial O (f16)

    const size_t need4 = ((size_t)5 << 20) + ((size_t)16 << 20) + ((size_t)1 << 20);
    const size_t need2 = ((size_t)5 << 20) + ((size_t)8 << 20) + ((size_t)1 << 19);

    hipLaunchKernelGGL(proj_kernel, dim3(512), dim3(256), 0, stream,
                       x, Kf, Kg, Kh, bf, bg, bh, fO, gO, hF);
    if (ws_size >= need4) {
        float* pml = (float*)((char*)d_ws + (21u << 20));
        hipLaunchKernelGGL((attn7_kernel<4>), dim3(1024), dim3(256), 0, stream,
                           fO, gO, hF, x, gamma, out, po, pml);
        hipLaunchKernelGGL((combine_kernel<4>), dim3(2048), dim3(256), 0, stream,
                           po, pml, x, gamma, out);
    } else if (ws_size >= need2) {
        float* pml = (float*)((char*)d_ws + (13u << 20));
        hipLaunchKernelGGL((attn7_kernel<2>), dim3(512), dim3(256), 0, stream,
                           fO, gO, hF, x, gamma, out, po, pml);
        hipLaunchKernelGGL((combine_kernel<2>), dim3(2048), dim3(256), 0, stream,
                           po, pml, x, gamma, out);
    } else {
        hipLaunchKernelGGL((attn7_kernel<1>), dim3(256), dim3(256), 0, stream,
                           fO, gO, hF, x, gamma, out, po, (float*)po);
    }
}

// Round 9
// 74.463 us; speedup vs baseline: 5.6456x; 1.1704x over previous
//
#include <hip/hip_runtime.h>

typedef _Float16 f16;
typedef _Float16 f16x8 __attribute__((ext_vector_type(8)));
typedef short s16x8 __attribute__((ext_vector_type(8)));      // 8 bf16 in 4 VGPRs
typedef float f32x4 __attribute__((ext_vector_type(4)));
typedef float f32x16 __attribute__((ext_vector_type(16)));
typedef unsigned int u32x4 __attribute__((ext_vector_type(4)));

#define LOG2E 1.44269504088896f
#define SM_OFF 16.0f   // fixed softmax offset (log2 units), baked into dim 8
#define MFMA32F16(a, b, c) __builtin_amdgcn_mfma_f32_32x32x16_f16(a, b, c, 0, 0, 0)
#define MFMA32BF16(a, b, c) __builtin_amdgcn_mfma_f32_32x32x16_bf16(a, b, c, 0, 0, 0)

typedef __attribute__((address_space(1))) const unsigned int* gas_t;
typedef __attribute__((address_space(3))) unsigned int* las_t;

// async global->LDS, 16B per lane: LDS dest = wave-uniform base + lane*16
static __device__ inline void gload16(const void* g, void* l) {
    __builtin_amdgcn_global_load_lds((gas_t)g, (las_t)l, 16, 0, 0);
}

// v_permlane32_swap_b32: a' = [a.row0 | b.row0], b' = [a.row1 | b.row1]
static __device__ inline void perm32swap(unsigned int& a, unsigned int& b) {
    asm("v_permlane32_swap_b32 %0, %1" : "+v"(a), "+v"(b));
}

// pack two f32 -> one u32 of two bf16 (lo = a, hi = b)
static __device__ inline unsigned int cvt_pk_bf16(float a, float b) {
    unsigned int r;
    asm("v_cvt_pk_bf16_f32 %0, %1, %2" : "=v"(r) : "v"(a), "v"(b));
    return r;
}

// scalar f32 -> bf16 (RNE)
static __device__ inline unsigned short f2bf(float f) {
    unsigned int u = __builtin_bit_cast(unsigned int, f);
    u += 0x7FFFu + ((u >> 16) & 1u);
    return (unsigned short)(u >> 16);
}

// ---------------- Kernel 1: projections ----------------
// fO/gO: [B*4096][16] f16. dims 0..7 = f / g*log2e; dim 8 = 1.0 (f) / -16.0 (g)
// so QK^T emits s*log2e - 16 directly (fixed-offset softmax, no running max).
// hF: h in BF16, fragment-major: per 16-key group [cb][nhalf][c&31][n&7].
__global__ __launch_bounds__(256) void proj_kernel(
    const float* __restrict__ x, const float* __restrict__ Kf,
    const float* __restrict__ Kg, const float* __restrict__ Kh,
    const float* __restrict__ bf, const float* __restrict__ bg,
    const float* __restrict__ bh,
    f16* __restrict__ fO, f16* __restrict__ gO, unsigned short* __restrict__ hF)
{
    __shared__ float KT[80 * 64];   // KT[c][d]: c<8 -> f, 8..15 -> g (scaled), 16..79 -> h
    __shared__ float bias[80];
    const int tid = threadIdx.x;

    for (int i = tid; i < 512; i += 256) {          // Kf/Kg are [64][8]
        int d = i >> 3, j = i & 7;
        KT[j * 64 + d] = Kf[i];
        KT[(8 + j) * 64 + d] = Kg[i] * LOG2E;
    }
    for (int i = tid; i < 4096; i += 256) {         // Kh is [64][64]
        int d = i >> 6, c = i & 63;
        KT[(16 + c) * 64 + d] = Kh[i];
    }
    if (tid < 8) { bias[tid] = bf[tid]; bias[8 + tid] = bg[tid] * LOG2E; }
    if (tid >= 16 && tid < 80) bias[tid] = bh[tid - 16];
    __syncthreads();

    const int quarter = tid >> 6;
    const int px = blockIdx.x * 64 + (tid & 63);    // pixel (b*4096 + n)
    const float4* xp = (const float4*)(x + (size_t)px * 64);
    float4 xr[16];
#pragma unroll
    for (int i = 0; i < 16; ++i) xr[i] = xp[i];

    float res[20];
    const int c0 = quarter * 20;
#pragma unroll
    for (int cc = 0; cc < 20; ++cc) {
        const int c = c0 + cc;
        float acc = bias[c];
        const float4* wv = (const float4*)(KT + c * 64);
#pragma unroll
        for (int i = 0; i < 16; ++i) {
            float4 w = wv[i];
            acc = fmaf(xr[i].x, w.x, acc);
            acc = fmaf(xr[i].y, w.y, acc);
            acc = fmaf(xr[i].z, w.z, acc);
            acc = fmaf(xr[i].w, w.w, acc);
        }
        res[cc] = acc;
    }

    const int b = px >> 12, n = px & 4095;
    const size_t hbase = (size_t)b * 262144 + (size_t)(n >> 4) * 1024
                       + (size_t)((n >> 3) & 1) * 256 + (n & 7);
    if (quarter == 0) {
        f16x8 fv, gv, fpad, gpad;
#pragma unroll
        for (int j = 0; j < 8; ++j) {
            fv[j] = (f16)res[j]; gv[j] = (f16)res[8 + j];
            fpad[j] = (f16)0.f;  gpad[j] = (f16)0.f;
        }
        fpad[0] = (f16)1.f;
        gpad[0] = (f16)(-SM_OFF);
        *(f16x8*)(fO + (size_t)px * 16)     = fv;
        *(f16x8*)(fO + (size_t)px * 16 + 8) = fpad;
        *(f16x8*)(gO + (size_t)px * 16)     = gv;
        *(f16x8*)(gO + (size_t)px * 16 + 8) = gpad;
#pragma unroll
        for (int cc = 16; cc < 20; ++cc) {
            const int hc = c0 + cc - 16;
            hF[hbase + (hc >> 5) * 512 + (hc & 31) * 8] = f2bf(res[cc]);
        }
    } else {
#pragma unroll
        for (int cc = 0; cc < 20; ++cc) {
            const int hc = c0 + cc - 16;
            hF[hbase + (hc >> 5) * 512 + (hc & 31) * 8] = f2bf(res[cc]);
        }
    }
}

// ---------------- Kernel 2: flash attention (offset softmax, bf16 p/h) --------
// Block = 4 waves x 32 q-rows. Per 64-key tile: h (8KB bf16) + f (2KB f16)
// staged into LDS via global_load_lds, double-buffered, one __syncthreads/iter.
// QK^T in f16 (16 k-dims: 8 data + offset dim) -> p = exp2(s) in f32 (range
// safe); l summed in f32; p packed to BF16 (wide exponent: no overflow at
// s_log2 up to ~40, no underflow on weak rows); PV via mfma_32x32x16_bf16.
template<int NSPLIT>
__global__ __launch_bounds__(256, 4) void attn9_kernel(
    const f16* __restrict__ fO, const f16* __restrict__ gO,
    const unsigned short* __restrict__ hF, const float* __restrict__ x,
    const float* __restrict__ gamma, float* __restrict__ out,
    unsigned short* __restrict__ po, float* __restrict__ pml)
{
    __shared__ __align__(16) char lds[2][10240];   // [buf][ h:8192 | f:2048 ]

    const int tid  = threadIdx.x;
    const int w    = tid >> 6;
    const int lane = tid & 63;
    const int q5   = lane & 31;
    const int hi   = lane >> 5;

    const int b = blockIdx.x & 7;
    int kc, qt;
    if (NSPLIT == 4)      { kc = (blockIdx.x >> 3) & 3; qt = blockIdx.x >> 5; }
    else if (NSPLIT == 2) { kc = (blockIdx.x >> 3) & 1; qt = blockIdx.x >> 4; }
    else                  { kc = 0;                     qt = blockIdx.x >> 3; }

    const int KEYS = 4096 / NSPLIT;
    const int NIT  = KEYS / 64;
    const int k0   = kc * KEYS;
    const int qrow = qt * 128 + w * 32 + q5;

    const char* hTile = (const char*)hF + ((size_t)b * 262144 + (size_t)k0 * 64) * 2;
    const char* fTile = (const char*)fO + ((size_t)b * 4096 + k0) * 32;

    // B operand: lane's k-half of g-row qrow (dims 0..7 data, dim 8 = -16, rest 0)
    const f16x8 gfrag = *(const f16x8*)(gO + ((size_t)b * 4096 + qrow) * 16 + hi * 8);

    f32x16 acc0, acc1;
#pragma unroll
    for (int i = 0; i < 16; ++i) { acc0[i] = 0.f; acc1[i] = 0.f; }
    float lpart = 0.f;

    // ---- stage tile 0 ----
    {
        const char* hg = hTile + w * 2048 + (size_t)lane * 16;
        char* hl = &lds[0][0] + w * 2048;
        gload16(hg, hl);
        gload16(hg + 1024, hl + 1024);
        if (w == 3) {
            const char* fg = fTile + (size_t)lane * 16;
            gload16(fg, &lds[0][8192]);
            gload16(fg + 1024, &lds[0][8192 + 1024]);
        }
    }
    __syncthreads();

    for (int t = 0; t < NIT; ++t) {
        const int cur = t & 1;
        if (t + 1 < NIT) {                          // issue next-tile stage (async)
            const char* hg = hTile + (size_t)(t + 1) * 8192 + w * 2048 + (size_t)lane * 16;
            char* hl = &lds[cur ^ 1][0] + w * 2048;
            gload16(hg, hl);
            gload16(hg + 1024, hl + 1024);
            if (w == 3) {
                const char* fg = fTile + (size_t)(t + 1) * 2048 + (size_t)lane * 16;
                gload16(fg, &lds[cur ^ 1][8192]);
                gload16(fg + 1024, &lds[cur ^ 1][8192 + 1024]);
            }
        }

        const unsigned short* hl = (const unsigned short*)&lds[cur][0];
        const f16* fl = (const f16*)&lds[cur][8192];

        // ---- QK^T: s[reg] = S[key][q]*log2e - 16, q = lane&31 ----
        const f16x8 fa0 = *(const f16x8*)(fl + q5 * 16 + hi * 8);         // keys 0..31
        const f16x8 fa1 = *(const f16x8*)(fl + (32 + q5) * 16 + hi * 8);  // keys 32..63
        f32x16 zc;
#pragma unroll
        for (int i = 0; i < 16; ++i) zc[i] = 0.f;
        f32x16 s0 = MFMA32F16(fa0, gfrag, zc);
        f32x16 s1 = MFMA32F16(fa1, gfrag, zc);

        // ---- fixed-offset softmax: p = exp2(s) in f32 ----
#pragma unroll
        for (int i = 0; i < 16; ++i) {
            s0[i] = exp2f(s0[i]);
            s1[i] = exp2f(s1[i]);
        }

        // ---- l partial: f32 tree over own 32 keys ----
        {
            float ls[16];
#pragma unroll
            for (int i = 0; i < 16; ++i) ls[i] = s0[i] + s1[i];
#pragma unroll
            for (int st = 8; st >= 1; st >>= 1)
#pragma unroll
                for (int i = 0; i < st; ++i) ls[i] += ls[i + st];
            lpart += ls[0];
        }

        // ---- pack to bf16 pairs (consecutive regs = consecutive keys) ----
        unsigned int wr[16];
#pragma unroll
        for (int i = 0; i < 8; ++i) {
            wr[i]     = cvt_pk_bf16(s0[2 * i], s0[2 * i + 1]);
            wr[8 + i] = cvt_pk_bf16(s1[2 * i], s1[2 * i + 1]);
        }

        // ---- assemble PV B-fragments in-register: 8 permlane32_swap ----
        perm32swap(wr[0], wr[2]);   perm32swap(wr[1], wr[3]);    // keys  0..15
        perm32swap(wr[4], wr[6]);   perm32swap(wr[5], wr[7]);    // keys 16..31
        perm32swap(wr[8], wr[10]);  perm32swap(wr[9], wr[11]);   // keys 32..47
        perm32swap(wr[12], wr[14]); perm32swap(wr[13], wr[15]);  // keys 48..63

        // ---- PV (bf16): O^T[c][q] += H^T[c][k] P^T[k][q], fragments from LDS ----
#pragma unroll
        for (int kk = 0; kk < 4; ++kk) {
            u32x4 tv;
            tv[0] = wr[kk * 4 + 0]; tv[1] = wr[kk * 4 + 1];
            tv[2] = wr[kk * 4 + 2]; tv[3] = wr[kk * 4 + 3];
            const s16x8 pf = __builtin_bit_cast(s16x8, tv);
            const s16x8 ha0 = *(const s16x8*)(hl + kk * 1024 + lane * 8);
            const s16x8 ha1 = *(const s16x8*)(hl + kk * 1024 + 512 + lane * 8);
            acc0 = MFMA32BF16(ha0, pf, acc0);
            acc1 = MFMA32BF16(ha1, pf, acc1);
        }

        if (t + 1 < NIT) __syncthreads();   // staged tile ready (full drain at barrier)
    }

    lpart += __shfl_xor(lpart, 32);

    if (NSPLIT == 1) {
        const float rin = 1.f / lpart;
        const float gm = gamma[0];
        const size_t qg = (size_t)b * 4096 + qrow;
#pragma unroll
        for (int cb = 0; cb < 2; ++cb)
#pragma unroll
            for (int r = 0; r < 4; ++r) {
                const size_t o = qg * 64 + cb * 32 + r * 8 + hi * 4;
                f32x4 v;
#pragma unroll
                for (int j = 0; j < 4; ++j) {
                    const float a = (cb == 0) ? acc0[4 * r + j] : acc1[4 * r + j];
                    v[j] = fmaf(gm, a * rin, x[o + j]);
                }
                *(f32x4*)(out + o) = v;
            }
    } else {
        unsigned short* pob = po + (size_t)((kc * 8 + b) * 128 + qt * 4 + w) * 2048;
#pragma unroll
        for (int cb = 0; cb < 2; ++cb)
#pragma unroll
            for (int r = 0; r < 4; ++r) {
                uint2 v;
                const float a0 = (cb == 0) ? acc0[4 * r + 0] : acc1[4 * r + 0];
                const float a1 = (cb == 0) ? acc0[4 * r + 1] : acc1[4 * r + 1];
                const float a2 = (cb == 0) ? acc0[4 * r + 2] : acc1[4 * r + 2];
                const float a3 = (cb == 0) ? acc0[4 * r + 3] : acc1[4 * r + 3];
                v.x = cvt_pk_bf16(a0, a1);
                v.y = cvt_pk_bf16(a2, a3);
                *(uint2*)(pob + (cb * 4 + r) * 256 + lane * 4) = v;
            }
        if (lane < 32)
            pml[(size_t)(kc * 8 + b) * 4096 + qrow] = lpart;
    }
}

// ---------------- Kernel 3: split-K combine (po in bf16, shared offset) -------
template<int NS>
__global__ __launch_bounds__(256) void combine_kernel(
    const unsigned short* __restrict__ po, const float* __restrict__ pml,
    const float* __restrict__ x, const float* __restrict__ gamma,
    float* __restrict__ out)
{
    const int t    = blockIdx.x * 256 + threadIdx.x;    // 524288 threads
    const int lane = t & 63;
    const int r    = (t >> 6) & 3;
    const int cb   = (t >> 8) & 1;
    const int w    = (t >> 9) & 3;
    const int qt   = (t >> 11) & 31;
    const int b    = (t >> 16) & 7;
    const int q    = qt * 128 + w * 32 + (lane & 31);
    const int c    = cb * 32 + r * 8 + (lane >> 5) * 4;

    float denom = 0.f;
    f32x4 num;
#pragma unroll
    for (int j = 0; j < 4; ++j) num[j] = 0.f;
#pragma unroll
    for (int kc = 0; kc < NS; ++kc) {
        denom += pml[(size_t)(kc * 8 + b) * 4096 + q];
        const uint2 v = *(const uint2*)(po + (size_t)((kc * 8 + b) * 128 + qt * 4 + w) * 2048
                                           + (cb * 4 + r) * 256 + lane * 4);
        num[0] += __builtin_bit_cast(float, v.x << 16);
        num[1] += __builtin_bit_cast(float, v.x & 0xFFFF0000u);
        num[2] += __builtin_bit_cast(float, v.y << 16);
        num[3] += __builtin_bit_cast(float, v.y & 0xFFFF0000u);
    }
    const float sc = gamma[0] / denom;
    const size_t o = ((size_t)b * 4096 + q) * 64 + c;
    const f32x4 xv = *(const f32x4*)(x + o);
    f32x4 ov;
#pragma unroll
    for (int j = 0; j < 4; ++j) ov[j] = fmaf(sc, num[j], xv[j]);
    *(f32x4*)(out + o) = ov;
}

extern "C" void kernel_launch(void* const* d_in, const int* in_sizes, int n_in,
                              void* d_out, int out_size, void* d_ws, size_t ws_size,
                              hipStream_t stream) {
    const float* x     = (const float*)d_in[0];
    const float* Kf    = (const float*)d_in[1];
    const float* Kg    = (const float*)d_in[2];
    const float* Kh    = (const float*)d_in[3];
    const float* bf    = (const float*)d_in[4];
    const float* bg    = (const float*)d_in[5];
    const float* bh    = (const float*)d_in[6];
    const float* gamma = (const float*)d_in[7];
    float* out = (float*)d_out;

    f16* fO = (f16*)d_ws;                                        // 1 MB ([px][16])
    f16* gO = (f16*)((char*)d_ws + (1 << 20));                   // 1 MB ([px][16])
    unsigned short* hF = (unsigned short*)((char*)d_ws + (2 << 20)); // 4 MB bf16
    unsigned short* po = (unsigned short*)((char*)d_ws + (6 << 20)); // NSPLIT*4 MB bf16

    const size_t need4 = ((size_t)6 << 20) + ((size_t)16 << 20) + ((size_t)1 << 20);
    const size_t need2 = ((size_t)6 << 20) + ((size_t)8 << 20) + ((size_t)1 << 19);

    hipLaunchKernelGGL(proj_kernel, dim3(512), dim3(256), 0, stream,
                       x, Kf, Kg, Kh, bf, bg, bh, fO, gO, hF);
    if (ws_size >= need4) {
        float* pml = (float*)((char*)d_ws + (22u << 20));
        hipLaunchKernelGGL((attn9_kernel<4>), dim3(1024), dim3(256), 0, stream,
                           fO, gO, hF, x, gamma, out, po, pml);
        hipLaunchKernelGGL((combine_kernel<4>), dim3(2048), dim3(256), 0, stream,
                           po, pml, x, gamma, out);
    } else if (ws_size >= need2) {
        float* pml = (float*)((char*)d_ws + (14u << 20));
        hipLaunchKernelGGL((attn9_kernel<2>), dim3(512), dim3(256), 0, stream,
                           fO, gO, hF, x, gamma, out, po, pml);
        hipLaunchKernelGGL((combine_kernel<2>), dim3(2048), dim3(256), 0, stream,
                           po, pml, x, gamma, out);
    } else {
        hipLaunchKernelGGL((attn9_kernel<1>), dim3(256), dim3(256), 0, stream,
                           fO, gO, hF, x, gamma, out, po, (float*)po);
    }
}

// Round 12
// 73.813 us; speedup vs baseline: 5.6953x; 1.0088x over previous
//
#include <hip/hip_runtime.h>

typedef _Float16 f16;
typedef _Float16 f16x8 __attribute__((ext_vector_type(8)));
typedef short s16x8 __attribute__((ext_vector_type(8)));      // 8 bf16 in 4 VGPRs
typedef float f32x4 __attribute__((ext_vector_type(4)));
typedef float f32x16 __attribute__((ext_vector_type(16)));
typedef unsigned int u32x4 __attribute__((ext_vector_type(4)));

#define LOG2E 1.44269504088896f
#define SM_OFF 16.0f   // fixed softmax offset (log2 units), baked into dim 8
#define MFMA32F16(a, b, c) __builtin_amdgcn_mfma_f32_32x32x16_f16(a, b, c, 0, 0, 0)
#define MFMA32BF16(a, b, c) __builtin_amdgcn_mfma_f32_32x32x16_bf16(a, b, c, 0, 0, 0)

typedef __attribute__((address_space(1))) const unsigned int* gas_t;
typedef __attribute__((address_space(3))) unsigned int* las_t;

// async global->LDS, 16B per lane: LDS dest = wave-uniform base + lane*16
static __device__ inline void gload16(const void* g, void* l) {
    __builtin_amdgcn_global_load_lds((gas_t)g, (las_t)l, 16, 0, 0);
}

// v_permlane32_swap_b32: a' = [a.row0 | b.row0], b' = [a.row1 | b.row1]
static __device__ inline void perm32swap(unsigned int& a, unsigned int& b) {
    asm("v_permlane32_swap_b32 %0, %1" : "+v"(a), "+v"(b));
}

// pack two f32 -> one u32 of two bf16 (lo = a, hi = b)
static __device__ inline unsigned int cvt_pk_bf16(float a, float b) {
    unsigned int r;
    asm("v_cvt_pk_bf16_f32 %0, %1, %2" : "=v"(r) : "v"(a), "v"(b));
    return r;
}

// NOTE (r10/r11 lesson): raw inline-asm v_exp_f32 violates the TRANS->VALU
// wait-state hazard (NaN at 0 nops, sporadic stale reads at s_nop 1). Use
// libm exp2f (r9-proven correct); revisit fast-exp only with verified fencing.

// scalar f32 -> bf16 (RNE)
static __device__ inline unsigned short f2bf(float f) {
    unsigned int u = __builtin_bit_cast(unsigned int, f);
    u += 0x7FFFu + ((u >> 16) & 1u);
    return (unsigned short)(u >> 16);
}

// ---------------- Kernel 1: projections ----------------
// fO/gO: [B*4096][16] f16. dims 0..7 = f / g*log2e; dim 8 = 1.0 (f) / -16.0 (g)
// so QK^T emits s*log2e - 16 directly (fixed-offset softmax, no running max).
// hF: h in BF16, fragment-major: per 16-key group [cb][nhalf][c&31][n&7].
__global__ __launch_bounds__(256) void proj_kernel(
    const float* __restrict__ x, const float* __restrict__ Kf,
    const float* __restrict__ Kg, const float* __restrict__ Kh,
    const float* __restrict__ bf, const float* __restrict__ bg,
    const float* __restrict__ bh,
    f16* __restrict__ fO, f16* __restrict__ gO, unsigned short* __restrict__ hF)
{
    __shared__ float KT[80 * 64];   // KT[c][d]: c<8 -> f, 8..15 -> g (scaled), 16..79 -> h
    __shared__ float bias[80];
    const int tid = threadIdx.x;

    for (int i = tid; i < 512; i += 256) {          // Kf/Kg are [64][8]
        int d = i >> 3, j = i & 7;
        KT[j * 64 + d] = Kf[i];
        KT[(8 + j) * 64 + d] = Kg[i] * LOG2E;
    }
    for (int i = tid; i < 4096; i += 256) {         // Kh is [64][64]
        int d = i >> 6, c = i & 63;
        KT[(16 + c) * 64 + d] = Kh[i];
    }
    if (tid < 8) { bias[tid] = bf[tid]; bias[8 + tid] = bg[tid] * LOG2E; }
    if (tid >= 16 && tid < 80) bias[tid] = bh[tid - 16];
    __syncthreads();

    const int quarter = tid >> 6;
    const int px = blockIdx.x * 64 + (tid & 63);    // pixel (b*4096 + n)
    const float4* xp = (const float4*)(x + (size_t)px * 64);
    float4 xr[16];
#pragma unroll
    for (int i = 0; i < 16; ++i) xr[i] = xp[i];

    float res[20];
    const int c0 = quarter * 20;
#pragma unroll
    for (int cc = 0; cc < 20; ++cc) {
        const int c = c0 + cc;
        float acc = bias[c];
        const float4* wv = (const float4*)(KT + c * 64);
#pragma unroll
        for (int i = 0; i < 16; ++i) {
            float4 w = wv[i];
            acc = fmaf(xr[i].x, w.x, acc);
            acc = fmaf(xr[i].y, w.y, acc);
            acc = fmaf(xr[i].z, w.z, acc);
            acc = fmaf(xr[i].w, w.w, acc);
        }
        res[cc] = acc;
    }

    const int b = px >> 12, n = px & 4095;
    const size_t hbase = (size_t)b * 262144 + (size_t)(n >> 4) * 1024
                       + (size_t)((n >> 3) & 1) * 256 + (n & 7);
    if (quarter == 0) {
        f16x8 fv, gv, fpad, gpad;
#pragma unroll
        for (int j = 0; j < 8; ++j) {
            fv[j] = (f16)res[j]; gv[j] = (f16)res[8 + j];
            fpad[j] = (f16)0.f;  gpad[j] = (f16)0.f;
        }
        fpad[0] = (f16)1.f;
        gpad[0] = (f16)(-SM_OFF);
        *(f16x8*)(fO + (size_t)px * 16)     = fv;
        *(f16x8*)(fO + (size_t)px * 16 + 8) = fpad;
        *(f16x8*)(gO + (size_t)px * 16)     = gv;
        *(f16x8*)(gO + (size_t)px * 16 + 8) = gpad;
#pragma unroll
        for (int cc = 16; cc < 20; ++cc) {
            const int hc = c0 + cc - 16;
            hF[hbase + (hc >> 5) * 512 + (hc & 31) * 8] = f2bf(res[cc]);
        }
    } else {
#pragma unroll
        for (int cc = 0; cc < 20; ++cc) {
            const int hc = c0 + cc - 16;
            hF[hbase + (hc >> 5) * 512 + (hc & 31) * 8] = f2bf(res[cc]);
        }
    }
}

// ---------------- Kernel 2: flash attention (offset softmax, split-K x8) ------
// Block = 4 waves x 32 q-rows. h (8KB bf16) double-buffered in LDS (16KB/block
// -> 8 blocks/CU co-resident); f read DIRECT from global (L2-resident) with
// one-iteration register prefetch. QK^T in f16 (8 data dims + offset dim) ->
// p = exp2(s) via libm exp2f; l in f32; p packed bf16 (cvt_pk_bf16 +
// permlane32_swap); PV via mfma_32x32x16_bf16 from LDS fragments.
template<int NSPLIT>
__global__ __launch_bounds__(256, 4) void attn12_kernel(
    const f16* __restrict__ fO, const f16* __restrict__ gO,
    const unsigned short* __restrict__ hF, const float* __restrict__ x,
    const float* __restrict__ gamma, float* __restrict__ out,
    unsigned short* __restrict__ po, float* __restrict__ pml)
{
    __shared__ __align__(16) char lds[2][8192];   // [buf][ h tile ]

    const int tid  = threadIdx.x;
    const int w    = tid >> 6;
    const int lane = tid & 63;
    const int q5   = lane & 31;
    const int hi   = lane >> 5;

    const int b = blockIdx.x & 7;
    int kc, qt;
    if (NSPLIT == 8)      { kc = (blockIdx.x >> 3) & 7; qt = blockIdx.x >> 6; }
    else if (NSPLIT == 4) { kc = (blockIdx.x >> 3) & 3; qt = blockIdx.x >> 5; }
    else if (NSPLIT == 2) { kc = (blockIdx.x >> 3) & 1; qt = blockIdx.x >> 4; }
    else                  { kc = 0;                     qt = blockIdx.x >> 3; }

    const int KEYS = 4096 / NSPLIT;
    const int NIT  = KEYS / 64;
    const int k0   = kc * KEYS;
    const int qrow = qt * 128 + w * 32 + q5;

    const char* hTile = (const char*)hF + ((size_t)b * 262144 + (size_t)k0 * 64) * 2;
    const f16*  fbase = fO + ((size_t)b * 4096 + k0) * 16;

    // B operand: lane's k-half of g-row qrow (dims 0..7 data, dim 8 = -16, rest 0)
    const f16x8 gfrag = *(const f16x8*)(gO + ((size_t)b * 4096 + qrow) * 16 + hi * 8);

    f32x16 acc0, acc1;
#pragma unroll
    for (int i = 0; i < 16; ++i) { acc0[i] = 0.f; acc1[i] = 0.f; }
    float lpart = 0.f;

#define STAGE_H(KT_, BI_) do {                                                  \
        const char* hg_ = hTile + (size_t)(KT_) * 8192 + w * 2048 + (size_t)lane * 16; \
        char* hl_ = &lds[BI_][0] + w * 2048;                                    \
        gload16(hg_, hl_);                                                      \
        gload16(hg_ + 1024, hl_ + 1024);                                        \
    } while (0)

    // ---- prologue: stage h tile 0; prefetch f tile 0 to regs ----
    STAGE_H(0, 0);
    f16x8 faA = *(const f16x8*)(fbase + (size_t)q5 * 16 + hi * 8);         // keys 0..31
    f16x8 faB = *(const f16x8*)(fbase + (size_t)(32 + q5) * 16 + hi * 8);  // keys 32..63
    __syncthreads();

    for (int t = 0; t < NIT; ++t) {
        const int cur = t & 1;
        if (t + 1 < NIT) STAGE_H(t + 1, cur ^ 1);   // async stage next h tile

        const f16x8 fa0 = faA, fa1 = faB;
        if (t + 1 < NIT) {                          // register-prefetch next f tile
            const f16* fp = fbase + (size_t)((t + 1) * 64 + q5) * 16 + hi * 8;
            faA = *(const f16x8*)(fp);
            faB = *(const f16x8*)(fp + 512);        // +32 rows * 16 f16
        }

        // ---- QK^T: s[reg] = S[key][q]*log2e - 16, q = lane&31 ----
        f32x16 zc;
#pragma unroll
        for (int i = 0; i < 16; ++i) zc[i] = 0.f;
        f32x16 s0 = MFMA32F16(fa0, gfrag, zc);
        f32x16 s1 = MFMA32F16(fa1, gfrag, zc);

        // ---- fixed-offset softmax: p = exp2(s) ----
#pragma unroll
        for (int i = 0; i < 16; ++i) {
            s0[i] = exp2f(s0[i]);
            s1[i] = exp2f(s1[i]);
        }

        // ---- l partial: f32 tree over own 32 keys ----
        {
            float ls[16];
#pragma unroll
            for (int i = 0; i < 16; ++i) ls[i] = s0[i] + s1[i];
#pragma unroll
            for (int st = 8; st >= 1; st >>= 1)
#pragma unroll
                for (int i = 0; i < st; ++i) ls[i] += ls[i + st];
            lpart += ls[0];
        }

        // ---- pack to bf16 pairs (consecutive regs = consecutive keys) ----
        unsigned int wr[16];
#pragma unroll
        for (int i = 0; i < 8; ++i) {
            wr[i]     = cvt_pk_bf16(s0[2 * i], s0[2 * i + 1]);
            wr[8 + i] = cvt_pk_bf16(s1[2 * i], s1[2 * i + 1]);
        }

        // ---- assemble PV B-fragments in-register: 8 permlane32_swap ----
        perm32swap(wr[0], wr[2]);   perm32swap(wr[1], wr[3]);    // keys  0..15
        perm32swap(wr[4], wr[6]);   perm32swap(wr[5], wr[7]);    // keys 16..31
        perm32swap(wr[8], wr[10]);  perm32swap(wr[9], wr[11]);   // keys 32..47
        perm32swap(wr[12], wr[14]); perm32swap(wr[13], wr[15]);  // keys 48..63

        // ---- PV (bf16): O^T[c][q] += H^T[c][k] P^T[k][q], fragments from LDS ----
        const unsigned short* hl = (const unsigned short*)&lds[cur][0];
#pragma unroll
        for (int kk = 0; kk < 4; ++kk) {
            u32x4 tv;
            tv[0] = wr[kk * 4 + 0]; tv[1] = wr[kk * 4 + 1];
            tv[2] = wr[kk * 4 + 2]; tv[3] = wr[kk * 4 + 3];
            const s16x8 pf = __builtin_bit_cast(s16x8, tv);
            const s16x8 ha0 = *(const s16x8*)(hl + kk * 1024 + lane * 8);
            const s16x8 ha1 = *(const s16x8*)(hl + kk * 1024 + 512 + lane * 8);
            acc0 = MFMA32BF16(ha0, pf, acc0);
            acc1 = MFMA32BF16(ha1, pf, acc1);
        }

        if (t + 1 < NIT) __syncthreads();   // staged tile ready (full drain at barrier)
    }
#undef STAGE_H

    lpart += __shfl_xor(lpart, 32);

    if (NSPLIT == 1) {
        const float rin = 1.f / lpart;
        const float gm = gamma[0];
        const size_t qg = (size_t)b * 4096 + qrow;
#pragma unroll
        for (int cb = 0; cb < 2; ++cb)
#pragma unroll
            for (int r = 0; r < 4; ++r) {
                const size_t o = qg * 64 + cb * 32 + r * 8 + hi * 4;
                f32x4 v;
#pragma unroll
                for (int j = 0; j < 4; ++j) {
                    const float a = (cb == 0) ? acc0[4 * r + j] : acc1[4 * r + j];
                    v[j] = fmaf(gm, a * rin, x[o + j]);
                }
                *(f32x4*)(out + o) = v;
            }
    } else {
        unsigned short* pob = po + (size_t)((kc * 8 + b) * 128 + qt * 4 + w) * 2048;
#pragma unroll
        for (int cb = 0; cb < 2; ++cb)
#pragma unroll
            for (int r = 0; r < 4; ++r) {
                uint2 v;
                const float a0 = (cb == 0) ? acc0[4 * r + 0] : acc1[4 * r + 0];
                const float a1 = (cb == 0) ? acc0[4 * r + 1] : acc1[4 * r + 1];
                const float a2 = (cb == 0) ? acc0[4 * r + 2] : acc1[4 * r + 2];
                const float a3 = (cb == 0) ? acc0[4 * r + 3] : acc1[4 * r + 3];
                v.x = cvt_pk_bf16(a0, a1);
                v.y = cvt_pk_bf16(a2, a3);
                *(uint2*)(pob + (cb * 4 + r) * 256 + lane * 4) = v;
            }
        if (lane < 32)
            pml[(size_t)(kc * 8 + b) * 4096 + qrow] = lpart;
    }
}

// ---------------- Kernel 3: split-K combine (po in bf16, shared offset) -------
template<int NS>
__global__ __launch_bounds__(256) void combine_kernel(
    const unsigned short* __restrict__ po, const float* __restrict__ pml,
    const float* __restrict__ x, const float* __restrict__ gamma,
    float* __restrict__ out)
{
    const int t    = blockIdx.x * 256 + threadIdx.x;    // 524288 threads
    const int lane = t & 63;
    const int r    = (t >> 6) & 3;
    const int cb   = (t >> 8) & 1;
    const int w    = (t >> 9) & 3;
    const int qt   = (t >> 11) & 31;
    const int b    = (t >> 16) & 7;
    const int q    = qt * 128 + w * 32 + (lane & 31);
    const int c    = cb * 32 + r * 8 + (lane >> 5) * 4;

    float denom = 0.f;
    f32x4 num;
#pragma unroll
    for (int j = 0; j < 4; ++j) num[j] = 0.f;
#pragma unroll
    for (int kc = 0; kc < NS; ++kc) {
        denom += pml[(size_t)(kc * 8 + b) * 4096 + q];
        const uint2 v = *(const uint2*)(po + (size_t)((kc * 8 + b) * 128 + qt * 4 + w) * 2048
                                           + (cb * 4 + r) * 256 + lane * 4);
        num[0] += __builtin_bit_cast(float, v.x << 16);
        num[1] += __builtin_bit_cast(float, v.x & 0xFFFF0000u);
        num[2] += __builtin_bit_cast(float, v.y << 16);
        num[3] += __builtin_bit_cast(float, v.y & 0xFFFF0000u);
    }
    const float sc = gamma[0] / denom;
    const size_t o = ((size_t)b * 4096 + q) * 64 + c;
    const f32x4 xv = *(const f32x4*)(x + o);
    f32x4 ov;
#pragma unroll
    for (int j = 0; j < 4; ++j) ov[j] = fmaf(sc, num[j], xv[j]);
    *(f32x4*)(out + o) = ov;
}

extern "C" void kernel_launch(void* const* d_in, const int* in_sizes, int n_in,
                              void* d_out, int out_size, void* d_ws, size_t ws_size,
                              hipStream_t stream) {
    const float* x     = (const float*)d_in[0];
    const float* Kf    = (const float*)d_in[1];
    const float* Kg    = (const float*)d_in[2];
    const float* Kh    = (const float*)d_in[3];
    const float* bf    = (const float*)d_in[4];
    const float* bg    = (const float*)d_in[5];
    const float* bh    = (const float*)d_in[6];
    const float* gamma = (const float*)d_in[7];
    float* out = (float*)d_out;

    f16* fO = (f16*)d_ws;                                        // 1 MB ([px][16])
    f16* gO = (f16*)((char*)d_ws + (1 << 20));                   // 1 MB ([px][16])
    unsigned short* hF = (unsigned short*)((char*)d_ws + (2 << 20)); // 4 MB bf16
    unsigned short* po = (unsigned short*)((char*)d_ws + (6 << 20)); // NSPLIT*4 MB bf16

    const size_t need8 = ((size_t)6 << 20) + ((size_t)32 << 20) + ((size_t)1 << 20);
    const size_t need4 = ((size_t)6 << 20) + ((size_t)16 << 20) + ((size_t)1 << 20);
    const size_t need2 = ((size_t)6 << 20) + ((size_t)8 << 20) + ((size_t)1 << 19);

    hipLaunchKernelGGL(proj_kernel, dim3(512), dim3(256), 0, stream,
                       x, Kf, Kg, Kh, bf, bg, bh, fO, gO, hF);
    if (ws_size >= need8) {
        float* pml = (float*)((char*)d_ws + (38u << 20));
        hipLaunchKernelGGL((attn12_kernel<8>), dim3(2048), dim3(256), 0, stream,
                           fO, gO, hF, x, gamma, out, po, pml);
        hipLaunchKernelGGL((combine_kernel<8>), dim3(2048), dim3(256), 0, stream,
                           po, pml, x, gamma, out);
    } else if (ws_size >= need4) {
        float* pml = (float*)((char*)d_ws + (22u << 20));
        hipLaunchKernelGGL((attn12_kernel<4>), dim3(1024), dim3(256), 0, stream,
                           fO, gO, hF, x, gamma, out, po, pml);
        hipLaunchKernelGGL((combine_kernel<4>), dim3(2048), dim3(256), 0, stream,
                           po, pml, x, gamma, out);
    } else if (ws_size >= need2) {
        float* pml = (float*)((char*)d_ws + (14u << 20));
        hipLaunchKernelGGL((attn12_kernel<2>), dim3(512), dim3(256), 0, stream,
                           fO, gO, hF, x, gamma, out, po, pml);
        hipLaunchKernelGGL((combine_kernel<2>), dim3(2048), dim3(256), 0, stream,
                           po, pml, x, gamma, out);
    } else {
        hipLaunchKernelGGL((attn12_kernel<1>), dim3(256), dim3(256), 0, stream,
                           fO, gO, hF, x, gamma, out, po, (float*)po);
    }
}

// Round 15
// 67.296 us; speedup vs baseline: 6.2468x; 1.0968x over previous
//
#include <hip/hip_runtime.h>

typedef _Float16 f16;
typedef _Float16 f16x8 __attribute__((ext_vector_type(8)));
typedef short s16x8 __attribute__((ext_vector_type(8)));      // 8 bf16 in 4 VGPRs
typedef float f32x4 __attribute__((ext_vector_type(4)));
typedef float f32x16 __attribute__((ext_vector_type(16)));
typedef unsigned int u32x4 __attribute__((ext_vector_type(4)));

#define SM_OFF_NAT 11.0903548889f   // fixed softmax offset, natural units (=16*ln2)
#define MFMA32F16(a, b, c) __builtin_amdgcn_mfma_f32_32x32x16_f16(a, b, c, 0, 0, 0)
#define MFMA32BF16(a, b, c) __builtin_amdgcn_mfma_f32_32x32x16_bf16(a, b, c, 0, 0, 0)

typedef __attribute__((address_space(1))) const unsigned int* gas_t;
typedef __attribute__((address_space(3))) unsigned int* las_t;

// async global->LDS, 16B per lane: LDS dest = wave-uniform base + lane*16
static __device__ inline void gload16(const void* g, void* l) {
    __builtin_amdgcn_global_load_lds((gas_t)g, (las_t)l, 16, 0, 0);
}

// v_permlane32_swap_b32: a' = [a.row0 | b.row0], b' = [a.row1 | b.row1]
static __device__ inline void perm32swap(unsigned int& a, unsigned int& b) {
    asm("v_permlane32_swap_b32 %0, %1" : "+v"(a), "+v"(b));
}

// pack two f32 -> one u32 of two bf16 (lo = a, hi = b). ONLY safe for non-TRANS
// producers (MFMA/VALU results) — see hazard note below.
static __device__ inline unsigned int cvt_pk_bf16(float a, float b) {
    unsigned int r;
    asm("v_cvt_pk_bf16_f32 %0, %1, %2" : "=v"(r) : "v"(a), "v"(b));
    return r;
}

// HAZARD MODEL (r9..r14 evidence): gfx950 TRANS ops (v_exp_f32) need wait
// states before a dependent consumer. The compiler inserts them for ITS OWN
// consumers but NOT for inline-asm reads (asm is opaque). Every failing round
// had asm (cvt_pk) consuming v_exp output directly; every passing round had a
// compiler VALU op in between. r13==r14 bit-identical absmax proves the
// "+0.0f" launder was folded (exp>=0). FIX: no inline asm may consume a TRANS
// result. p-packing below uses compiler builtins only:
//   round-half-up: u += 0x8000 (v_add, compiler-protected consumer of exp)
//   pack hi16s:    v_perm_b32 via __builtin_amdgcn_perm, sel 0x07060302
static __device__ inline unsigned int pack_bf16_pair(float a, float b) {
    unsigned int ua = __builtin_bit_cast(unsigned int, a) + 0x8000u;
    unsigned int ub = __builtin_bit_cast(unsigned int, b) + 0x8000u;
    return __builtin_amdgcn_perm(ub, ua, 0x07060302u);  // {ub.b3,ub.b2,ua.b3,ua.b2}
}

// scalar f32 -> bf16 (RNE)
static __device__ inline unsigned short f2bf(float f) {
    unsigned int u = __builtin_bit_cast(unsigned int, f);
    u += 0x7FFFu + ((u >> 16) & 1u);
    return (unsigned short)(u >> 16);
}

// ---------------- Kernel 1: projections ----------------
// fO/gO: [B*4096][16] f16, NATURAL units. dims 0..7 = f / g; dim 8 = 1.0 (f) /
// -11.0904 (g) so QK^T emits s - 11.0904 directly (fixed-offset softmax; the
// offset is row-uniform so its f16 rounding cancels exactly in p/sum(p)).
// hF: h in BF16, fragment-major: per 16-key group [cb][nhalf][c&31][n&7].
__global__ __launch_bounds__(256) void proj_kernel(
    const float* __restrict__ x, const float* __restrict__ Kf,
    const float* __restrict__ Kg, const float* __restrict__ Kh,
    const float* __restrict__ bf, const float* __restrict__ bg,
    const float* __restrict__ bh,
    f16* __restrict__ fO, f16* __restrict__ gO, unsigned short* __restrict__ hF)
{
    __shared__ float KT[80 * 64];   // KT[c][d]: c<8 -> f, 8..15 -> g, 16..79 -> h
    __shared__ float bias[80];
    const int tid = threadIdx.x;

    for (int i = tid; i < 512; i += 256) {          // Kf/Kg are [64][8]
        int d = i >> 3, j = i & 7;
        KT[j * 64 + d] = Kf[i];
        KT[(8 + j) * 64 + d] = Kg[i];
    }
    for (int i = tid; i < 4096; i += 256) {         // Kh is [64][64]
        int d = i >> 6, c = i & 63;
        KT[(16 + c) * 64 + d] = Kh[i];
    }
    if (tid < 8) { bias[tid] = bf[tid]; bias[8 + tid] = bg[tid]; }
    if (tid >= 16 && tid < 80) bias[tid] = bh[tid - 16];
    __syncthreads();

    const int quarter = tid >> 6;
    const int px = blockIdx.x * 64 + (tid & 63);    // pixel (b*4096 + n)
    const float4* xp = (const float4*)(x + (size_t)px * 64);
    float4 xr[16];
#pragma unroll
    for (int i = 0; i < 16; ++i) xr[i] = xp[i];

    float res[20];
    const int c0 = quarter * 20;
#pragma unroll
    for (int cc = 0; cc < 20; ++cc) {
        const int c = c0 + cc;
        float acc = bias[c];
        const float4* wv = (const float4*)(KT + c * 64);
#pragma unroll
        for (int i = 0; i < 16; ++i) {
            float4 w = wv[i];
            acc = fmaf(xr[i].x, w.x, acc);
            acc = fmaf(xr[i].y, w.y, acc);
            acc = fmaf(xr[i].z, w.z, acc);
            acc = fmaf(xr[i].w, w.w, acc);
        }
        res[cc] = acc;
    }

    const int b = px >> 12, n = px & 4095;
    const size_t hbase = (size_t)b * 262144 + (size_t)(n >> 4) * 1024
                       + (size_t)((n >> 3) & 1) * 256 + (n & 7);
    if (quarter == 0) {
        f16x8 fv, gv, fpad, gpad;
#pragma unroll
        for (int j = 0; j < 8; ++j) {
            fv[j] = (f16)res[j]; gv[j] = (f16)res[8 + j];
            fpad[j] = (f16)0.f;  gpad[j] = (f16)0.f;
        }
        fpad[0] = (f16)1.f;
        gpad[0] = (f16)(-SM_OFF_NAT);
        *(f16x8*)(fO + (size_t)px * 16)     = fv;
        *(f16x8*)(fO + (size_t)px * 16 + 8) = fpad;
        *(f16x8*)(gO + (size_t)px * 16)     = gv;
        *(f16x8*)(gO + (size_t)px * 16 + 8) = gpad;
#pragma unroll
        for (int cc = 16; cc < 20; ++cc) {
            const int hc = c0 + cc - 16;
            hF[hbase + (hc >> 5) * 512 + (hc & 31) * 8] = f2bf(res[cc]);
        }
    } else {
#pragma unroll
        for (int cc = 0; cc < 20; ++cc) {
            const int hc = c0 + cc - 16;
            hF[hbase + (hc >> 5) * 512 + (hc & 31) * 8] = f2bf(res[cc]);
        }
    }
}

// ---------------- Kernel 2: flash attention (offset softmax, native exp) ------
// Block = 4 waves x 32 q-rows. h (8KB bf16) double-buffered in LDS; f read
// DIRECT from global (L2-resident) with one-iteration register prefetch.
// QK^T in f16 (8 data dims + offset dim, natural units) -> p = __expf(s)
// (v_mul + v_exp); l in f32 tree (compiler consumers, hazard-safe); p packed
// to bf16 via add+v_perm builtins (NO asm touches TRANS results); PV via
// mfma_32x32x16_bf16 from LDS fragments.
template<int NSPLIT>
__global__ __launch_bounds__(256, 4) void attn15_kernel(
    const f16* __restrict__ fO, const f16* __restrict__ gO,
    const unsigned short* __restrict__ hF, const float* __restrict__ x,
    const float* __restrict__ gamma, float* __restrict__ out,
    unsigned short* __restrict__ po, float* __restrict__ pml)
{
    __shared__ __align__(16) char lds[2][8192];   // [buf][ h tile ]

    const int tid  = threadIdx.x;
    const int w    = tid >> 6;
    const int lane = tid & 63;
    const int q5   = lane & 31;
    const int hi   = lane >> 5;

    const int b = blockIdx.x & 7;
    int kc, qt;
    if (NSPLIT == 8)      { kc = (blockIdx.x >> 3) & 7; qt = blockIdx.x >> 6; }
    else if (NSPLIT == 4) { kc = (blockIdx.x >> 3) & 3; qt = blockIdx.x >> 5; }
    else if (NSPLIT == 2) { kc = (blockIdx.x >> 3) & 1; qt = blockIdx.x >> 4; }
    else                  { kc = 0;                     qt = blockIdx.x >> 3; }

    const int KEYS = 4096 / NSPLIT;
    const int NIT  = KEYS / 64;
    const int k0   = kc * KEYS;
    const int qrow = qt * 128 + w * 32 + q5;

    const char* hTile = (const char*)hF + ((size_t)b * 262144 + (size_t)k0 * 64) * 2;
    const f16*  fbase = fO + ((size_t)b * 4096 + k0) * 16;

    // B operand: lane's k-half of g-row qrow (dims 0..7 data, dim 8 = -11.09, rest 0)
    const f16x8 gfrag = *(const f16x8*)(gO + ((size_t)b * 4096 + qrow) * 16 + hi * 8);

    f32x16 acc0, acc1;
#pragma unroll
    for (int i = 0; i < 16; ++i) { acc0[i] = 0.f; acc1[i] = 0.f; }
    float lpart = 0.f;

#define STAGE_H(KT_, BI_) do {                                                  \
        const char* hg_ = hTile + (size_t)(KT_) * 8192 + w * 2048 + (size_t)lane * 16; \
        char* hl_ = &lds[BI_][0] + w * 2048;                                    \
        gload16(hg_, hl_);                                                      \
        gload16(hg_ + 1024, hl_ + 1024);                                        \
    } while (0)

    // ---- prologue: stage h tile 0; prefetch f tile 0 to regs ----
    STAGE_H(0, 0);
    f16x8 faA = *(const f16x8*)(fbase + (size_t)q5 * 16 + hi * 8);         // keys 0..31
    f16x8 faB = *(const f16x8*)(fbase + (size_t)(32 + q5) * 16 + hi * 8);  // keys 32..63
    __syncthreads();

    for (int t = 0; t < NIT; ++t) {
        const int cur = t & 1;
        if (t + 1 < NIT) STAGE_H(t + 1, cur ^ 1);   // async stage next h tile

        const f16x8 fa0 = faA, fa1 = faB;
        if (t + 1 < NIT) {                          // register-prefetch next f tile
            const f16* fp = fbase + (size_t)((t + 1) * 64 + q5) * 16 + hi * 8;
            faA = *(const f16x8*)(fp);
            faB = *(const f16x8*)(fp + 512);        // +32 rows * 16 f16
        }

        // ---- QK^T: s[reg] = S[key][q] - 11.09 (natural units), q = lane&31 ----
        f32x16 zc;
#pragma unroll
        for (int i = 0; i < 16; ++i) zc[i] = 0.f;
        f32x16 s0 = MFMA32F16(fa0, gfrag, zc);
        f32x16 s1 = MFMA32F16(fa1, gfrag, zc);

        // ---- fixed-offset softmax: p = __expf(s) (native v_mul+v_exp) ----
#pragma unroll
        for (int i = 0; i < 16; ++i) {
            s0[i] = __expf(s0[i]);
            s1[i] = __expf(s1[i]);
        }

        // ---- l partial: f32 tree over own 32 keys (compiler consumers) ----
        {
            float ls[16];
#pragma unroll
            for (int i = 0; i < 16; ++i) ls[i] = s0[i] + s1[i];
#pragma unroll
            for (int st = 8; st >= 1; st >>= 1)
#pragma unroll
                for (int i = 0; i < st; ++i) ls[i] += ls[i + st];
            lpart += ls[0];
        }

        // ---- pack to bf16 pairs via builtins (no asm on TRANS results) ----
        unsigned int wr[16];
#pragma unroll
        for (int i = 0; i < 8; ++i) {
            wr[i]     = pack_bf16_pair(s0[2 * i], s0[2 * i + 1]);
            wr[8 + i] = pack_bf16_pair(s1[2 * i], s1[2 * i + 1]);
        }

        // ---- assemble PV B-fragments in-register: 8 permlane32_swap ----
        // (inputs are v_add/v_perm outputs — non-TRANS, asm-safe)
        perm32swap(wr[0], wr[2]);   perm32swap(wr[1], wr[3]);    // keys  0..15
        perm32swap(wr[4], wr[6]);   perm32swap(wr[5], wr[7]);    // keys 16..31
        perm32swap(wr[8], wr[10]);  perm32swap(wr[9], wr[11]);   // keys 32..47
        perm32swap(wr[12], wr[14]); perm32swap(wr[13], wr[15]);  // keys 48..63

        // ---- PV (bf16): O^T[c][q] += H^T[c][k] P^T[k][q], fragments from LDS ----
        const unsigned short* hl = (const unsigned short*)&lds[cur][0];
#pragma unroll
        for (int kk = 0; kk < 4; ++kk) {
            u32x4 tv;
            tv[0] = wr[kk * 4 + 0]; tv[1] = wr[kk * 4 + 1];
            tv[2] = wr[kk * 4 + 2]; tv[3] = wr[kk * 4 + 3];
            const s16x8 pf = __builtin_bit_cast(s16x8, tv);
            const s16x8 ha0 = *(const s16x8*)(hl + kk * 1024 + lane * 8);
            const s16x8 ha1 = *(const s16x8*)(hl + kk * 1024 + 512 + lane * 8);
            acc0 = MFMA32BF16(ha0, pf, acc0);
            acc1 = MFMA32BF16(ha1, pf, acc1);
        }

        if (t + 1 < NIT) __syncthreads();   // staged tile ready (full drain at barrier)
    }
#undef STAGE_H

    lpart += __shfl_xor(lpart, 32);

    if (NSPLIT == 1) {
        const float rin = 1.f / lpart;
        const float gm = gamma[0];
        const size_t qg = (size_t)b * 4096 + qrow;
#pragma unroll
        for (int cb = 0; cb < 2; ++cb)
#pragma unroll
            for (int r = 0; r < 4; ++r) {
                const size_t o = qg * 64 + cb * 32 + r * 8 + hi * 4;
                f32x4 v;
#pragma unroll
                for (int j = 0; j < 4; ++j) {
                    const float a = (cb == 0) ? acc0[4 * r + j] : acc1[4 * r + j];
                    v[j] = fmaf(gm, a * rin, x[o + j]);
                }
                *(f32x4*)(out + o) = v;
            }
    } else {
        unsigned short* pob = po + (size_t)((kc * 8 + b) * 128 + qt * 4 + w) * 2048;
#pragma unroll
        for (int cb = 0; cb < 2; ++cb)
#pragma unroll
            for (int r = 0; r < 4; ++r) {
                uint2 v;
                const float a0 = (cb == 0) ? acc0[4 * r + 0] : acc1[4 * r + 0];
                const float a1 = (cb == 0) ? acc0[4 * r + 1] : acc1[4 * r + 1];
                const float a2 = (cb == 0) ? acc0[4 * r + 2] : acc1[4 * r + 2];
                const float a3 = (cb == 0) ? acc0[4 * r + 3] : acc1[4 * r + 3];
                v.x = cvt_pk_bf16(a0, a1);      // MFMA-result consumers: asm-safe
                v.y = cvt_pk_bf16(a2, a3);
                *(uint2*)(pob + (cb * 4 + r) * 256 + lane * 4) = v;
            }
        if (lane < 32)
            pml[(size_t)(kc * 8 + b) * 4096 + qrow] = lpart;
    }
}

// ---------------- Kernel 3: split-K combine (po in bf16, shared offset) -------
template<int NS>
__global__ __launch_bounds__(256) void combine_kernel(
    const unsigned short* __restrict__ po, const float* __restrict__ pml,
    const float* __restrict__ x, const float* __restrict__ gamma,
    float* __restrict__ out)
{
    const int t    = blockIdx.x * 256 + threadIdx.x;    // 524288 threads
    const int lane = t & 63;
    const int r    = (t >> 6) & 3;
    const int cb   = (t >> 8) & 1;
    const int w    = (t >> 9) & 3;
    const int qt   = (t >> 11) & 31;
    const int b    = (t >> 16) & 7;
    const int q    = qt * 128 + w * 32 + (lane & 31);
    const int c    = cb * 32 + r * 8 + (lane >> 5) * 4;

    float denom = 0.f;
    f32x4 num;
#pragma unroll
    for (int j = 0; j < 4; ++j) num[j] = 0.f;
#pragma unroll
    for (int kc = 0; kc < NS; ++kc) {
        denom += pml[(size_t)(kc * 8 + b) * 4096 + q];
        const uint2 v = *(const uint2*)(po + (size_t)((kc * 8 + b) * 128 + qt * 4 + w) * 2048
                                           + (cb * 4 + r) * 256 + lane * 4);
        num[0] += __builtin_bit_cast(float, v.x << 16);
        num[1] += __builtin_bit_cast(float, v.x & 0xFFFF0000u);
        num[2] += __builtin_bit_cast(float, v.y << 16);
        num[3] += __builtin_bit_cast(float, v.y & 0xFFFF0000u);
    }
    const float sc = gamma[0] / denom;
    const size_t o = ((size_t)b * 4096 + q) * 64 + c;
    const f32x4 xv = *(const f32x4*)(x + o);
    f32x4 ov;
#pragma unroll
    for (int j = 0; j < 4; ++j) ov[j] = fmaf(sc, num[j], xv[j]);
    *(f32x4*)(out + o) = ov;
}

extern "C" void kernel_launch(void* const* d_in, const int* in_sizes, int n_in,
                              void* d_out, int out_size, void* d_ws, size_t ws_size,
                              hipStream_t stream) {
    const float* x     = (const float*)d_in[0];
    const float* Kf    = (const float*)d_in[1];
    const float* Kg    = (const float*)d_in[2];
    const float* Kh    = (const float*)d_in[3];
    const float* bf    = (const float*)d_in[4];
    const float* bg    = (const float*)d_in[5];
    const float* bh    = (const float*)d_in[6];
    const float* gamma = (const float*)d_in[7];
    float* out = (float*)d_out;

    f16* fO = (f16*)d_ws;                                        // 1 MB ([px][16])
    f16* gO = (f16*)((char*)d_ws + (1 << 20));                   // 1 MB ([px][16])
    unsigned short* hF = (unsigned short*)((char*)d_ws + (2 << 20)); // 4 MB bf16
    unsigned short* po = (unsigned short*)((char*)d_ws + (6 << 20)); // NSPLIT*4 MB bf16

    const size_t need4 = ((size_t)6 << 20) + ((size_t)16 << 20) + ((size_t)1 << 20);
    const size_t need2 = ((size_t)6 << 20) + ((size_t)8 << 20) + ((size_t)1 << 19);

    hipLaunchKernelGGL(proj_kernel, dim3(512), dim3(256), 0, stream,
                       x, Kf, Kg, Kh, bf, bg, bh, fO, gO, hF);
    if (ws_size >= need4) {
        float* pml = (float*)((char*)d_ws + (22u << 20));
        hipLaunchKernelGGL((attn15_kernel<4>), dim3(1024), dim3(256), 0, stream,
                           fO, gO, hF, x, gamma, out, po, pml);
        hipLaunchKernelGGL((combine_kernel<4>), dim3(2048), dim3(256), 0, stream,
                           po, pml, x, gamma, out);
    } else if (ws_size >= need2) {
        float* pml = (float*)((char*)d_ws + (14u << 20));
        hipLaunchKernelGGL((attn15_kernel<2>), dim3(512), dim3(256), 0, stream,
                           fO, gO, hF, x, gamma, out, po, pml);
        hipLaunchKernelGGL((combine_kernel<2>), dim3(2048), dim3(256), 0, stream,
                           po, pml, x, gamma, out);
    } else {
        hipLaunchKernelGGL((attn15_kernel<1>), dim3(256), dim3(256), 0, stream,
                           fO, gO, hF, x, gamma, out, po, (float*)po);
    }
}